// Round 3
// baseline (83.238 us; speedup 1.0000x reference)
//
#include <hip/hip_runtime.h>
#include <hip/hip_cooperative_groups.h>
#include <math.h>

namespace cg = cooperative_groups;

// ---------------------------------------------------------------------------
// Problem constants (from reference)
// ---------------------------------------------------------------------------
#define IN_DIM   16
#define CD       7
#define SAMPS    20
#define KFILT    101
#define SIGLEN   140      // CD * SAMPS
#define MCONST   128      // 2^CD

// ws layout (bytes):
//   [0      .. NB*8)  : double partials[NB]
//   [262144 .. +392)  : double G[49]

// ---------------------------------------------------------------------------
// Single cooperative kernel:
//   blocks [0, NB)      : phase1 encoder (enc stays in registers) + partials
//   blocks [NB, NB+7)   : phase1 G column (data-independent conv chain)
//   grid.sync()
//   blocks [0, NB)      : phase2 reduce partials -> norm (deterministic,
//                         identical in every block), modulate, channel G*s,
//                         demod, noise, decoder, store out
// ---------------------------------------------------------------------------
__global__ __launch_bounds__(256, 3) void k_fused(
    const float* __restrict__ x,
    const float* __restrict__ We1, const float* __restrict__ be1,
    const float* __restrict__ We2, const float* __restrict__ be2,
    const float* __restrict__ Wd1, const float* __restrict__ bd1,
    const float* __restrict__ Wd2, const float* __restrict__ bd2,
    const float* __restrict__ h_lp, const float* __restrict__ h_ps,
    const float* __restrict__ noise, const int* __restrict__ snr_p,
    double* __restrict__ partials, double* __restrict__ Gd,
    float* __restrict__ out, int B, int NB)
{
    cg::grid_group grid = cg::this_grid();
    int t   = threadIdx.x;
    int bid = blockIdx.x;

    __shared__ float  sA[256];            // phase1: We1   | phase2: Wd2
    __shared__ float  sB[112];            // phase1: We2   | phase2: Wd1
    __shared__ float  sb1[16], sb2[7];    // encoder biases
    __shared__ float  sc1[16], sc2[16];   // decoder biases
    __shared__ double red[256];
    __shared__ double sG[49];
    __shared__ float  str[2 * MCONST];
    __shared__ float  snorm, sdenom;
    __shared__ double cur[SIGLEN], nxt[SIGLEN];
    __shared__ float  hA[KFILT], hB[KFILT];   // h_ps, h_lp

    float e[CD];
    int row = bid * 256 + t;

    if (bid < NB) {
        // ---------------- phase 1: encoder ----------------
        if (t < 256) sA[t]  = We1[t];
        if (t < 112) sB[t]  = We2[t];
        if (t < 16)  sb1[t] = be1[t];
        if (t < 7)   sb2[t] = be2[t];
        __syncthreads();

        double ss = 0.0;
        if (row < B) {
            const float4* xp = reinterpret_cast<const float4*>(x + (size_t)row * IN_DIM);
            float4 v0 = xp[0], v1 = xp[1], v2 = xp[2], v3 = xp[3];
            float xr[16] = {v0.x,v0.y,v0.z,v0.w, v1.x,v1.y,v1.z,v1.w,
                            v2.x,v2.y,v2.z,v2.w, v3.x,v3.y,v3.z,v3.w};
            float h[16];
            #pragma unroll
            for (int i = 0; i < 16; ++i) {
                float acc = sb1[i];
                #pragma unroll
                for (int j = 0; j < 16; ++j) acc = fmaf(sA[i*16+j], xr[j], acc);
                h[i] = (acc >= 0.f) ? acc : 0.01f * acc;
            }
            #pragma unroll
            for (int o = 0; o < CD; ++o) {
                float acc = sb2[o];
                #pragma unroll
                for (int i = 0; i < 16; ++i) acc = fmaf(sB[o*16+i], h[i], acc);
                e[o] = acc;
                ss += (double)acc * (double)acc;
            }
        }
        red[t] = ss;
        __syncthreads();
        #pragma unroll
        for (int s = 128; s > 0; s >>= 1) {
            if (t < s) red[t] += red[t + s];
            __syncthreads();
        }
        if (t == 0) partials[bid] = red[0];
    } else {
        // ---------------- phase 1: G column `basis` ----------------
        int basis = bid - NB;
        if (t < KFILT) { hA[t] = h_ps[t]; hB[t] = h_lp[t]; }
        __syncthreads();
        // conv(delta_at(20*basis), h_ps) = shifted h_ps (truncated)
        if (t < SIGLEN) {
            int m = t + 50 - SAMPS * basis;
            cur[t] = (m >= 0 && m < KFILT) ? (double)hA[m] : 0.0;
        }
        __syncthreads();
        for (int f = 0; f < 2; ++f) {
            const float* h = (f == 0) ? hB : hA;   // lowpass, then pulseshape
            if (t < SIGLEN) {
                double acc = 0.0;
                for (int m = 0; m < KFILT; ++m) {
                    int j = t + 50 - m;
                    if (j >= 0 && j < SIGLEN) acc += (double)h[m] * cur[j];
                }
                nxt[t] = acc;
            }
            __syncthreads();
            if (t < SIGLEN) cur[t] = nxt[t];
            __syncthreads();
        }
        if (t < CD) Gd[t * CD + basis] = (double)SAMPS * cur[t * SAMPS];
    }

    grid.sync();

    if (bid >= NB) return;

    // ---------------- phase 2 ----------------
    if (t < 256) sA[t] = Wd2[t];
    if (t < 112) sB[t] = Wd1[t];
    if (t < 16)  { sc1[t] = bd1[t]; sc2[t] = bd2[t]; }
    if (t < 49)  sG[t] = Gd[t];
    if (t < MCONST) {
        float ph = (float)(2.0 * 3.14159265358979323846 / (double)MCONST) * (float)t;
        str[t]          = cosf(ph);
        str[MCONST + t] = sinf(ph);
    }
    {
        double s = 0.0;
        for (int i = t; i < NB; i += 256) s += partials[i];
        red[t] = s;
    }
    __syncthreads();
    #pragma unroll
    for (int k = 128; k > 0; k >>= 1) {
        if (t < k) red[t] += red[t + k];
        __syncthreads();
    }
    if (t == 0) {
        snorm = (float)sqrt(red[0]);
        int iv = *snr_p;
        float sv = (iv >= -1000 && iv <= 1000) ? (float)iv
                                               : *reinterpret_cast<const float*>(snr_p);
        float snr_lin = powf(10.0f, 0.1f * sv);
        sdenom = sqrtf((float)(8.0 / 7.0) * snr_lin);  // sqrt(2*rate*snr_lin), rate=4/7
    }
    __syncthreads();

    if (row >= B) return;

    float sr[CD], si[CD], sgn[CD];
    #pragma unroll
    for (int o = 0; o < CD; ++o) {
        float es = e[o] / snorm * 70.0f;         // enc / ||enc|| * 70
        float rv = rintf(es);                    // jnp.round = half-to-even
        int xi = (int)rv;
        sgn[o] = (xi < 0) ? -1.0f : 1.0f;
        int idx = (xi < 0 ? -xi : xi) & (MCONST - 1);   // mod(|xi|, 128)
        sr[o] = str[idx];
        si[o] = str[MCONST + idx];
    }

    // channel: y = G * s, demodulate
    float res[CD];
    #pragma unroll
    for (int k = 0; k < CD; ++k) {
        double yr = 0.0, yi = 0.0;
        #pragma unroll
        for (int c = 0; c < CD; ++c) {
            double g = sG[k * CD + c];
            yr += g * (double)sr[c];
            yi += g * (double)si[c];
        }
        float ang = atan2f((float)yi, (float)yr);
        float q = ang * (float)(128.0 / (2.0 * 3.14159265358979323846));
        float r = rintf(q);
        float m = fmodf(r, 128.0f);
        if (m < 0.0f) m += 128.0f;               // jnp.mod semantics
        res[k] = m * sgn[k] + noise[(size_t)row * CD + k] / sdenom;
    }

    // decoder
    float dd[16];
    #pragma unroll
    for (int i = 0; i < 16; ++i) {
        float acc = sc1[i];
        #pragma unroll
        for (int c = 0; c < CD; ++c) acc = fmaf(sB[i*CD+c], res[c], acc);
        dd[i] = (acc >= 0.f) ? acc : 0.01f * acc;
    }
    float4* op = reinterpret_cast<float4*>(out + (size_t)row * IN_DIM);
    #pragma unroll
    for (int q4 = 0; q4 < 4; ++q4) {
        float o0[4];
        #pragma unroll
        for (int u = 0; u < 4; ++u) {
            int i = q4 * 4 + u;
            float acc = sc2[i];
            #pragma unroll
            for (int j = 0; j < 16; ++j) acc = fmaf(sA[i*16+j], dd[j], acc);
            o0[u] = acc;
        }
        op[q4] = make_float4(o0[0], o0[1], o0[2], o0[3]);
    }
}

// ---------------------------------------------------------------------------
extern "C" void kernel_launch(void* const* d_in, const int* in_sizes, int n_in,
                              void* d_out, int out_size, void* d_ws, size_t ws_size,
                              hipStream_t stream)
{
    const float* x    = (const float*)d_in[0];
    const float* We1  = (const float*)d_in[1];
    const float* be1  = (const float*)d_in[2];
    const float* We2  = (const float*)d_in[3];
    const float* be2  = (const float*)d_in[4];
    const float* Wd1  = (const float*)d_in[5];
    const float* bd1  = (const float*)d_in[6];
    const float* Wd2  = (const float*)d_in[7];
    const float* bd2  = (const float*)d_in[8];
    const float* h_lp = (const float*)d_in[9];
    const float* h_ps = (const float*)d_in[10];
    const float* noise= (const float*)d_in[11];
    const int*   snr  = (const int*)d_in[12];
    float* out = (float*)d_out;

    int B  = in_sizes[0] / IN_DIM;
    int NB = (B + 255) / 256;   // 512 for B=131072

    char* ws = (char*)d_ws;
    double* partials = (double*)(ws + 0);
    double* Gd       = (double*)(ws + 262144);

    void* args[] = {
        (void*)&x, (void*)&We1, (void*)&be1, (void*)&We2, (void*)&be2,
        (void*)&Wd1, (void*)&bd1, (void*)&Wd2, (void*)&bd2,
        (void*)&h_lp, (void*)&h_ps, (void*)&noise, (void*)&snr,
        (void*)&partials, (void*)&Gd, (void*)&out, (void*)&B, (void*)&NB
    };
    hipLaunchCooperativeKernel((const void*)k_fused, dim3(NB + CD), dim3(256),
                               args, 0, stream);
}

// Round 4
// 61.150 us; speedup vs baseline: 1.3612x; 1.3612x over previous
//
#include <hip/hip_runtime.h>
#include <math.h>

// ---------------------------------------------------------------------------
// Problem constants (from reference)
// ---------------------------------------------------------------------------
#define IN_DIM   16
#define CD       7
#define SAMPS    20
#define KFILT    101
#define SIGLEN   140      // CD * SAMPS
#define MCONST   128      // 2^CD

// ws layout (bytes):
//   [0    .. 4096)  : double partials[512]
//   [4096 .. 4488)  : double G[49]
//   [8192 .. 8200)  : unsigned bar[2] = {arrival counter, release flag}
//                     (zeroed via hipMemsetAsync at every launch)

// ---------------------------------------------------------------------------
// Single kernel, manual grid barrier.
//   grid = NB blocks (exactly; G computed by blocks 0..6 alongside their rows)
//   phase 1: encoder (enc kept in registers), block-tree partial sum-sq,
//            blocks 0..6 additionally push one basis vector through the
//            truncated 3-conv chain -> column of G
//   barrier: syncthreads -> t0 {threadfence(agent); atomicAdd; last sets flag;
//            others spin with s_sleep}
//   phase 2: redundant deterministic norm reduction (agent-scope loads),
//            modulate via trig table, y = G*s (f64), atan2 demod, noise,
//            decoder, store out
// ---------------------------------------------------------------------------
__global__ __launch_bounds__(256, 2) void k_fused(
    const float* __restrict__ x,
    const float* __restrict__ We1, const float* __restrict__ be1,
    const float* __restrict__ We2, const float* __restrict__ be2,
    const float* __restrict__ Wd1, const float* __restrict__ bd1,
    const float* __restrict__ Wd2, const float* __restrict__ bd2,
    const float* __restrict__ h_lp, const float* __restrict__ h_ps,
    const float* __restrict__ noise, const int* __restrict__ snr_p,
    double* __restrict__ partials, double* __restrict__ Gd,
    unsigned* __restrict__ bar,
    float* __restrict__ out, int B, int NB)
{
    int t   = threadIdx.x;
    int bid = blockIdx.x;
    int row = bid * 256 + t;

    __shared__ float  sA[256];            // phase1: We1   | phase2: Wd2
    __shared__ float  sB[112];            // phase1: We2   | phase2: Wd1
    __shared__ float  sb1[16], sb2r[7];   // encoder biases
    __shared__ float  sc1[16], sc2[16];   // decoder biases
    __shared__ double red[256];
    __shared__ double sG[49];
    __shared__ float  str[2 * MCONST];
    __shared__ float  snorm, sdenom;
    __shared__ double cur[SIGLEN], nxt[SIGLEN];
    __shared__ float  hA[KFILT], hB[KFILT];   // h_ps, h_lp

    // ---------------- phase 1 loads ----------------
    sA[t] = We1[t];
    if (t < 112) sB[t]  = We2[t];
    if (t < 16)  sb1[t] = be1[t];
    if (t < 7)   sb2r[t] = be2[t];
    if (bid < CD && t < KFILT) { hA[t] = h_ps[t]; hB[t] = h_lp[t]; }
    __syncthreads();

    // ---------------- phase 1: encoder ----------------
    float e[CD];
    double ss = 0.0;
    if (row < B) {
        const float4* xp = reinterpret_cast<const float4*>(x + (size_t)row * IN_DIM);
        float4 v0 = xp[0], v1 = xp[1], v2 = xp[2], v3 = xp[3];
        float xr[16] = {v0.x,v0.y,v0.z,v0.w, v1.x,v1.y,v1.z,v1.w,
                        v2.x,v2.y,v2.z,v2.w, v3.x,v3.y,v3.z,v3.w};
        float h[16];
        #pragma unroll
        for (int i = 0; i < 16; ++i) {
            float acc = sb1[i];
            #pragma unroll
            for (int j = 0; j < 16; ++j) acc = fmaf(sA[i*16+j], xr[j], acc);
            h[i] = (acc >= 0.f) ? acc : 0.01f * acc;
        }
        #pragma unroll
        for (int o = 0; o < CD; ++o) {
            float acc = sb2r[o];
            #pragma unroll
            for (int i = 0; i < 16; ++i) acc = fmaf(sB[o*16+i], h[i], acc);
            e[o] = acc;
            ss += (double)acc * (double)acc;
        }
    }
    red[t] = ss;
    __syncthreads();
    #pragma unroll
    for (int s = 128; s > 0; s >>= 1) {
        if (t < s) red[t] += red[t + s];
        __syncthreads();
    }
    if (t == 0) partials[bid] = red[0];

    // ---------------- phase 1: G column (blocks 0..6) ----------------
    if (bid < CD) {
        // conv(delta_at(20*bid), h_ps) = shifted h_ps (truncated)
        if (t < SIGLEN) {
            int m = t + 50 - SAMPS * bid;
            cur[t] = (m >= 0 && m < KFILT) ? (double)hA[m] : 0.0;
        }
        __syncthreads();
        for (int f = 0; f < 2; ++f) {
            const float* h = (f == 0) ? hB : hA;   // lowpass, then pulseshape
            if (t < SIGLEN) {
                double acc = 0.0;
                for (int m = 0; m < KFILT; ++m) {
                    int j = t + 50 - m;
                    if (j >= 0 && j < SIGLEN) acc += (double)h[m] * cur[j];
                }
                nxt[t] = acc;
            }
            __syncthreads();
            if (t < SIGLEN) cur[t] = nxt[t];
            __syncthreads();
        }
        if (t < CD) Gd[t * CD + bid] = (double)SAMPS * cur[t * SAMPS];
    }

    // ---------------- manual grid barrier ----------------
    __syncthreads();   // all block stores (partials, Gd) complete to L2
    if (t == 0) {
        __threadfence();   // agent-scope release: flush XCD L2 writebacks
        unsigned old = __hip_atomic_fetch_add(&bar[0], 1u, __ATOMIC_ACQ_REL,
                                              __HIP_MEMORY_SCOPE_AGENT);
        if (old == (unsigned)(NB - 1)) {
            __hip_atomic_store(&bar[1], 1u, __ATOMIC_RELEASE,
                               __HIP_MEMORY_SCOPE_AGENT);
        } else {
            while (__hip_atomic_load(&bar[1], __ATOMIC_ACQUIRE,
                                     __HIP_MEMORY_SCOPE_AGENT) == 0u) {
                __builtin_amdgcn_s_sleep(2);
            }
        }
    }
    __syncthreads();

    // ---------------- phase 2 ----------------
    sA[t] = Wd2[t];
    if (t < 112) sB[t] = Wd1[t];
    if (t < 16)  { sc1[t] = bd1[t]; sc2[t] = bd2[t]; }
    if (t < 49)  sG[t] = __hip_atomic_load(&Gd[t], __ATOMIC_RELAXED,
                                           __HIP_MEMORY_SCOPE_AGENT);
    if (t < MCONST) {
        float ph = (float)(2.0 * 3.14159265358979323846 / (double)MCONST) * (float)t;
        str[t]          = cosf(ph);
        str[MCONST + t] = sinf(ph);
    }
    {
        double s = 0.0;
        for (int i = t; i < NB; i += 256)
            s += __hip_atomic_load(&partials[i], __ATOMIC_RELAXED,
                                   __HIP_MEMORY_SCOPE_AGENT);
        red[t] = s;
    }
    __syncthreads();
    #pragma unroll
    for (int k = 128; k > 0; k >>= 1) {
        if (t < k) red[t] += red[t + k];
        __syncthreads();
    }
    if (t == 0) {
        snorm = (float)sqrt(red[0]);
        int iv = *snr_p;
        float sv = (iv >= -1000 && iv <= 1000) ? (float)iv
                                               : *reinterpret_cast<const float*>(snr_p);
        float snr_lin = powf(10.0f, 0.1f * sv);
        sdenom = sqrtf((float)(8.0 / 7.0) * snr_lin);  // sqrt(2*rate*snr_lin), rate=4/7
    }
    __syncthreads();

    if (row >= B) return;

    float sr[CD], si[CD], sgn[CD];
    #pragma unroll
    for (int o = 0; o < CD; ++o) {
        float es = e[o] / snorm * 70.0f;         // enc / ||enc|| * 70
        float rv = rintf(es);                    // jnp.round = half-to-even
        int xi = (int)rv;
        sgn[o] = (xi < 0) ? -1.0f : 1.0f;
        int idx = (xi < 0 ? -xi : xi) & (MCONST - 1);   // mod(|xi|, 128)
        sr[o] = str[idx];
        si[o] = str[MCONST + idx];
    }

    // channel: y = G * s, demodulate
    float res[CD];
    #pragma unroll
    for (int k = 0; k < CD; ++k) {
        double yr = 0.0, yi = 0.0;
        #pragma unroll
        for (int c = 0; c < CD; ++c) {
            double g = sG[k * CD + c];
            yr += g * (double)sr[c];
            yi += g * (double)si[c];
        }
        float ang = atan2f((float)yi, (float)yr);
        float q = ang * (float)(128.0 / (2.0 * 3.14159265358979323846));
        float r = rintf(q);
        float m = fmodf(r, 128.0f);
        if (m < 0.0f) m += 128.0f;               // jnp.mod semantics
        res[k] = m * sgn[k] + noise[(size_t)row * CD + k] / sdenom;
    }

    // decoder
    float dd[16];
    #pragma unroll
    for (int i = 0; i < 16; ++i) {
        float acc = sc1[i];
        #pragma unroll
        for (int c = 0; c < CD; ++c) acc = fmaf(sB[i*CD+c], res[c], acc);
        dd[i] = (acc >= 0.f) ? acc : 0.01f * acc;
    }
    float4* op = reinterpret_cast<float4*>(out + (size_t)row * IN_DIM);
    #pragma unroll
    for (int q4 = 0; q4 < 4; ++q4) {
        float o0[4];
        #pragma unroll
        for (int u = 0; u < 4; ++u) {
            int i = q4 * 4 + u;
            float acc = sc2[i];
            #pragma unroll
            for (int j = 0; j < 16; ++j) acc = fmaf(sA[i*16+j], dd[j], acc);
            o0[u] = acc;
        }
        op[q4] = make_float4(o0[0], o0[1], o0[2], o0[3]);
    }
}

// ---------------------------------------------------------------------------
extern "C" void kernel_launch(void* const* d_in, const int* in_sizes, int n_in,
                              void* d_out, int out_size, void* d_ws, size_t ws_size,
                              hipStream_t stream)
{
    const float* x    = (const float*)d_in[0];
    const float* We1  = (const float*)d_in[1];
    const float* be1  = (const float*)d_in[2];
    const float* We2  = (const float*)d_in[3];
    const float* be2  = (const float*)d_in[4];
    const float* Wd1  = (const float*)d_in[5];
    const float* bd1  = (const float*)d_in[6];
    const float* Wd2  = (const float*)d_in[7];
    const float* bd2  = (const float*)d_in[8];
    const float* h_lp = (const float*)d_in[9];
    const float* h_ps = (const float*)d_in[10];
    const float* noise= (const float*)d_in[11];
    const int*   snr  = (const int*)d_in[12];
    float* out = (float*)d_out;

    int B  = in_sizes[0] / IN_DIM;
    int NB = (B + 255) / 256;   // 512 for B=131072 -> exactly 2 blocks/CU

    char* ws = (char*)d_ws;
    double*   partials = (double*)(ws + 0);
    double*   Gd       = (double*)(ws + 4096);
    unsigned* bar      = (unsigned*)(ws + 8192);

    // reset barrier state (graph-capturable, ~16B)
    hipMemsetAsync(bar, 0, 2 * sizeof(unsigned), stream);

    k_fused<<<NB, 256, 0, stream>>>(x, We1, be1, We2, be2, Wd1, bd1, Wd2, bd2,
                                    h_lp, h_ps, noise, snr,
                                    partials, Gd, bar, out, B, NB);
}

// Round 5
// 38.785 us; speedup vs baseline: 2.1461x; 1.5766x over previous
//
#include <hip/hip_runtime.h>
#include <math.h>

// ---------------------------------------------------------------------------
// Problem constants (from reference)
// ---------------------------------------------------------------------------
#define IN_DIM   16
#define CD       7
#define SAMPS    20
#define KFILT    101
#define SIGLEN   140      // CD * SAMPS
#define MCONST   128      // 2^CD

// ws layout (bytes):
//   [0    .. 4096)  : double partials[512]   (agent-scope atomic access only)
//   [4096 .. 4488)  : double G[49]           (agent-scope atomic access only)
//   [8192 .. 8200)  : unsigned bar[2] = {arrival counter, release flag}
//                     (zeroed via hipMemsetAsync at every launch)

// ---------------------------------------------------------------------------
// Single kernel, manual grid barrier with NO agent-scope acquire/release
// fences (no buffer_inv / buffer_wbl2 storms):
//   - all cross-block data goes through agent-scope RELAXED atomics (LLC)
//   - arrival = s_waitcnt vmcnt(0) + relaxed fetch_add
//   - spin   = relaxed load + s_sleep(16)
// Everything not depending on the norm is hoisted before the barrier.
// ---------------------------------------------------------------------------
__global__ __launch_bounds__(256, 2) void k_fused(
    const float* __restrict__ x,
    const float* __restrict__ We1, const float* __restrict__ be1,
    const float* __restrict__ We2, const float* __restrict__ be2,
    const float* __restrict__ Wd1, const float* __restrict__ bd1,
    const float* __restrict__ Wd2, const float* __restrict__ bd2,
    const float* __restrict__ h_lp, const float* __restrict__ h_ps,
    const float* __restrict__ noise, const int* __restrict__ snr_p,
    double* __restrict__ partials, double* __restrict__ Gd,
    unsigned* __restrict__ bar,
    float* __restrict__ out, int B, int NB)
{
    int t   = threadIdx.x;
    int bid = blockIdx.x;
    int row = bid * 256 + t;

    __shared__ float  sWe1[256], sWe2[112], sb1[16], sb2r[7];
    __shared__ float  sWd1[112], sWd2[256], sc1[16], sc2[16];
    __shared__ float  snz[256 * CD];          // staged noise rows
    __shared__ double red[256];
    __shared__ double sG[49];
    __shared__ float  str[2 * MCONST];
    __shared__ float  snorm, sdenom;
    __shared__ double cur[SIGLEN], nxt[SIGLEN];
    __shared__ float  hA[KFILT], hB[KFILT];   // h_ps, h_lp

    // ---------------- phase 1 loads ----------------
    sWe1[t] = We1[t];
    if (t < 112) sWe2[t] = We2[t];
    if (t < 16)  sb1[t]  = be1[t];
    if (t < 7)   sb2r[t] = be2[t];
    if (bid < CD && t < KFILT) { hA[t] = h_ps[t]; hB[t] = h_lp[t]; }
    __syncthreads();

    // ---------------- phase 1: encoder ----------------
    float e[CD];
    double ss = 0.0;
    if (row < B) {
        const float4* xp = reinterpret_cast<const float4*>(x + (size_t)row * IN_DIM);
        float4 v0 = xp[0], v1 = xp[1], v2 = xp[2], v3 = xp[3];
        float xr[16] = {v0.x,v0.y,v0.z,v0.w, v1.x,v1.y,v1.z,v1.w,
                        v2.x,v2.y,v2.z,v2.w, v3.x,v3.y,v3.z,v3.w};
        float h[16];
        #pragma unroll
        for (int i = 0; i < 16; ++i) {
            float acc = sb1[i];
            #pragma unroll
            for (int j = 0; j < 16; ++j) acc = fmaf(sWe1[i*16+j], xr[j], acc);
            h[i] = (acc >= 0.f) ? acc : 0.01f * acc;
        }
        #pragma unroll
        for (int o = 0; o < CD; ++o) {
            float acc = sb2r[o];
            #pragma unroll
            for (int i = 0; i < 16; ++i) acc = fmaf(sWe2[o*16+i], h[i], acc);
            e[o] = acc;
            ss += (double)acc * (double)acc;
        }
    }
    red[t] = ss;
    __syncthreads();
    #pragma unroll
    for (int s = 128; s > 0; s >>= 1) {
        if (t < s) red[t] += red[t + s];
        __syncthreads();
    }
    if (t == 0)
        __hip_atomic_store(&partials[bid], red[0], __ATOMIC_RELAXED,
                           __HIP_MEMORY_SCOPE_AGENT);

    // ---------------- phase 1: G column (blocks 0..6) ----------------
    if (bid < CD) {
        // conv(delta_at(20*bid), h_ps) = shifted h_ps (truncated)
        if (t < SIGLEN) {
            int m = t + 50 - SAMPS * bid;
            cur[t] = (m >= 0 && m < KFILT) ? (double)hA[m] : 0.0;
        }
        __syncthreads();
        for (int f = 0; f < 2; ++f) {
            const float* h = (f == 0) ? hB : hA;   // lowpass, then pulseshape
            if (t < SIGLEN) {
                double acc = 0.0;
                for (int m = 0; m < KFILT; ++m) {
                    int j = t + 50 - m;
                    if (j >= 0 && j < SIGLEN) acc += (double)h[m] * cur[j];
                }
                nxt[t] = acc;
            }
            __syncthreads();
            if (t < SIGLEN) cur[t] = nxt[t];
            __syncthreads();
        }
        if (t < CD)
            __hip_atomic_store(&Gd[t * CD + bid], (double)SAMPS * cur[t * SAMPS],
                               __ATOMIC_RELAXED, __HIP_MEMORY_SCOPE_AGENT);
    }

    // ---------------- pre-barrier hoisted work (norm-independent) ----------
    if (t < 112) sWd1[t] = Wd1[t];
    sWd2[t] = Wd2[t];
    if (t < 16)  { sc1[t] = bd1[t]; sc2[t] = bd2[t]; }
    if (t < MCONST) {
        float ph = (float)(2.0 * 3.14159265358979323846 / (double)MCONST) * (float)t;
        str[t]          = cosf(ph);
        str[MCONST + t] = sinf(ph);
    }
    {   // stage this block's noise rows, coalesced
        size_t base = (size_t)bid * (256 * CD);
        size_t lim  = (size_t)B * CD;
        #pragma unroll
        for (int i = 0; i < CD; ++i) {
            int idx = t + i * 256;
            if (base + idx < lim) snz[idx] = noise[base + idx];
        }
    }
    if (t == 1) {
        int iv = *snr_p;
        float sv = (iv >= -1000 && iv <= 1000) ? (float)iv
                                               : *reinterpret_cast<const float*>(snr_p);
        float snr_lin = powf(10.0f, 0.1f * sv);
        sdenom = sqrtf((float)(8.0 / 7.0) * snr_lin);  // sqrt(2*rate*snr_lin), rate=4/7
    }

    // ---------------- manual grid barrier (no inv/wb) ----------------
    __syncthreads();   // all waves done with phase-1 global stores issued
    if (t == 0) {
        asm volatile("s_waitcnt vmcnt(0)" ::: "memory");   // own stores at LLC
        unsigned old = __hip_atomic_fetch_add(&bar[0], 1u, __ATOMIC_RELAXED,
                                              __HIP_MEMORY_SCOPE_AGENT);
        if (old == (unsigned)(NB - 1)) {
            __hip_atomic_store(&bar[1], 1u, __ATOMIC_RELAXED,
                               __HIP_MEMORY_SCOPE_AGENT);
        } else {
            while (__hip_atomic_load(&bar[1], __ATOMIC_RELAXED,
                                     __HIP_MEMORY_SCOPE_AGENT) == 0u) {
                __builtin_amdgcn_s_sleep(16);
            }
        }
    }
    __syncthreads();

    // ---------------- phase 2: norm reduction (identical in every block) ----
    if (t < 49)  sG[t] = __hip_atomic_load(&Gd[t], __ATOMIC_RELAXED,
                                           __HIP_MEMORY_SCOPE_AGENT);
    {
        double s = 0.0;
        for (int i = t; i < NB; i += 256)
            s += __hip_atomic_load(&partials[i], __ATOMIC_RELAXED,
                                   __HIP_MEMORY_SCOPE_AGENT);
        red[t] = s;
    }
    __syncthreads();
    #pragma unroll
    for (int k = 128; k > 0; k >>= 1) {
        if (t < k) red[t] += red[t + k];
        __syncthreads();
    }
    if (t == 0) snorm = (float)sqrt(red[0]);
    __syncthreads();

    if (row >= B) return;

    float sr[CD], si[CD], sgn[CD];
    #pragma unroll
    for (int o = 0; o < CD; ++o) {
        float es = e[o] / snorm * 70.0f;         // enc / ||enc|| * 70
        float rv = rintf(es);                    // jnp.round = half-to-even
        int xi = (int)rv;
        sgn[o] = (xi < 0) ? -1.0f : 1.0f;
        int idx = (xi < 0 ? -xi : xi) & (MCONST - 1);   // mod(|xi|, 128)
        sr[o] = str[idx];
        si[o] = str[MCONST + idx];
    }

    // channel: y = G * s, demodulate, noise
    float res[CD];
    #pragma unroll
    for (int k = 0; k < CD; ++k) {
        double yr = 0.0, yi = 0.0;
        #pragma unroll
        for (int c = 0; c < CD; ++c) {
            double g = sG[k * CD + c];
            yr += g * (double)sr[c];
            yi += g * (double)si[c];
        }
        float ang = atan2f((float)yi, (float)yr);
        float q = ang * (float)(128.0 / (2.0 * 3.14159265358979323846));
        float r = rintf(q);
        float m = fmodf(r, 128.0f);
        if (m < 0.0f) m += 128.0f;               // jnp.mod semantics
        res[k] = m * sgn[k] + snz[t * CD + k] / sdenom;
    }

    // decoder
    float dd[16];
    #pragma unroll
    for (int i = 0; i < 16; ++i) {
        float acc = sc1[i];
        #pragma unroll
        for (int c = 0; c < CD; ++c) acc = fmaf(sWd1[i*CD+c], res[c], acc);
        dd[i] = (acc >= 0.f) ? acc : 0.01f * acc;
    }
    float4* op = reinterpret_cast<float4*>(out + (size_t)row * IN_DIM);
    #pragma unroll
    for (int q4 = 0; q4 < 4; ++q4) {
        float o0[4];
        #pragma unroll
        for (int u = 0; u < 4; ++u) {
            int i = q4 * 4 + u;
            float acc = sc2[i];
            #pragma unroll
            for (int j = 0; j < 16; ++j) acc = fmaf(sWd2[i*16+j], dd[j], acc);
            o0[u] = acc;
        }
        op[q4] = make_float4(o0[0], o0[1], o0[2], o0[3]);
    }
}

// ---------------------------------------------------------------------------
extern "C" void kernel_launch(void* const* d_in, const int* in_sizes, int n_in,
                              void* d_out, int out_size, void* d_ws, size_t ws_size,
                              hipStream_t stream)
{
    const float* x    = (const float*)d_in[0];
    const float* We1  = (const float*)d_in[1];
    const float* be1  = (const float*)d_in[2];
    const float* We2  = (const float*)d_in[3];
    const float* be2  = (const float*)d_in[4];
    const float* Wd1  = (const float*)d_in[5];
    const float* bd1  = (const float*)d_in[6];
    const float* Wd2  = (const float*)d_in[7];
    const float* bd2  = (const float*)d_in[8];
    const float* h_lp = (const float*)d_in[9];
    const float* h_ps = (const float*)d_in[10];
    const float* noise= (const float*)d_in[11];
    const int*   snr  = (const int*)d_in[12];
    float* out = (float*)d_out;

    int B  = in_sizes[0] / IN_DIM;
    int NB = (B + 255) / 256;   // 512 for B=131072 -> exactly 2 blocks/CU

    char* ws = (char*)d_ws;
    double*   partials = (double*)(ws + 0);
    double*   Gd       = (double*)(ws + 4096);
    unsigned* bar      = (unsigned*)(ws + 8192);

    // reset barrier state (graph-capturable, 8B)
    hipMemsetAsync(bar, 0, 2 * sizeof(unsigned), stream);

    k_fused<<<NB, 256, 0, stream>>>(x, We1, be1, We2, be2, Wd1, bd1, Wd2, bd2,
                                    h_lp, h_ps, noise, snr,
                                    partials, Gd, bar, out, B, NB);
}

// Round 8
// 38.283 us; speedup vs baseline: 2.1743x; 1.0131x over previous
//
#include <hip/hip_runtime.h>
#include <math.h>

// ---------------------------------------------------------------------------
// Problem constants (from reference)
// ---------------------------------------------------------------------------
#define IN_DIM   16
#define CD       7
#define SAMPS    20
#define KFILT    101
#define SIGLEN   140      // CD * SAMPS
#define MCONST   128      // 2^CD
#define NREP     8        // replication factor for cross-block data

// ws layout (bytes), NB <= 512:
//   [0     .. 32768)  : double partialsR[NREP][NB]   (agent-relaxed atomics)
//   [32768 .. 36864)  : double GR[NREP][64]          (agent-relaxed atomics)
//   [36864 .. 38912)  : u32 L0[g] @ 36864 + g*256, g<8   arrival level 0
//   [38912 .. 38916)  : u32 root counter
//   [39168 .. 41216)  : u32 flag[r] @ 39168 + r*256, r<8 replicated release
//   memset [36864 .. 41216) each launch
// ---------------------------------------------------------------------------

__device__ __forceinline__ unsigned ld_u32(const void* p) {
    return __hip_atomic_load((const unsigned*)p, __ATOMIC_RELAXED,
                             __HIP_MEMORY_SCOPE_AGENT);
}
__device__ __forceinline__ void st_u32(void* p, unsigned v) {
    __hip_atomic_store((unsigned*)p, v, __ATOMIC_RELAXED,
                       __HIP_MEMORY_SCOPE_AGENT);
}
__device__ __forceinline__ unsigned add_u32(void* p) {
    return __hip_atomic_fetch_add((unsigned*)p, 1u, __ATOMIC_RELAXED,
                                  __HIP_MEMORY_SCOPE_AGENT);
}
__device__ __forceinline__ double ld_f64(const void* p) {
    return __hip_atomic_load((const double*)p, __ATOMIC_RELAXED,
                             __HIP_MEMORY_SCOPE_AGENT);
}
__device__ __forceinline__ void st_f64(void* p, double v) {
    __hip_atomic_store((double*)p, v, __ATOMIC_RELAXED,
                       __HIP_MEMORY_SCOPE_AGENT);
}

__global__ __launch_bounds__(256, 2) void k_fused(
    const float* __restrict__ x,
    const float* __restrict__ We1, const float* __restrict__ be1,
    const float* __restrict__ We2, const float* __restrict__ be2,
    const float* __restrict__ Wd1, const float* __restrict__ bd1,
    const float* __restrict__ Wd2, const float* __restrict__ bd2,
    const float* __restrict__ h_lp, const float* __restrict__ h_ps,
    const float* __restrict__ noise, const int* __restrict__ snr_p,
    double* __restrict__ partialsR, double* __restrict__ GR,
    char* __restrict__ barBase,
    float* __restrict__ out, int B, int NB)
{
    int t   = threadIdx.x;
    int bid = blockIdx.x;
    int row = bid * 256 + t;
    int rep = bid & (NREP - 1);

    __shared__ float  sWe1[256], sWe2[112], sb1[16], sb2r[7];
    __shared__ float  sWd1[112], sWd2[256], sc1[16], sc2[16];
    __shared__ float  snz[256 * CD];          // staged noise rows
    __shared__ double red[256];
    __shared__ double sG[49];
    __shared__ float  snorm, sdenom;
    __shared__ float  str[2 * MCONST];
    __shared__ double cur[SIGLEN], nxt[SIGLEN];
    __shared__ float  hA[KFILT], hB[KFILT];   // h_ps, h_lp

    // ---------------- phase 1 loads ----------------
    sWe1[t] = We1[t];
    if (t < 112) sWe2[t] = We2[t];
    if (t < 16)  sb1[t]  = be1[t];
    if (t < 7)   sb2r[t] = be2[t];
    if (bid < CD && t < KFILT) { hA[t] = h_ps[t]; hB[t] = h_lp[t]; }
    __syncthreads();

    // ---------------- phase 1: encoder ----------------
    float e[CD];
    double ss = 0.0;
    if (row < B) {
        const float4* xp = reinterpret_cast<const float4*>(x + (size_t)row * IN_DIM);
        float4 v0 = xp[0], v1 = xp[1], v2 = xp[2], v3 = xp[3];
        float xr[16] = {v0.x,v0.y,v0.z,v0.w, v1.x,v1.y,v1.z,v1.w,
                        v2.x,v2.y,v2.z,v2.w, v3.x,v3.y,v3.z,v3.w};
        float h[16];
        #pragma unroll
        for (int i = 0; i < 16; ++i) {
            float acc = sb1[i];
            #pragma unroll
            for (int j = 0; j < 16; ++j) acc = fmaf(sWe1[i*16+j], xr[j], acc);
            h[i] = (acc >= 0.f) ? acc : 0.01f * acc;
        }
        #pragma unroll
        for (int o = 0; o < CD; ++o) {
            float acc = sb2r[o];
            #pragma unroll
            for (int i = 0; i < 16; ++i) acc = fmaf(sWe2[o*16+i], h[i], acc);
            e[o] = acc;
            ss += (double)acc * (double)acc;
        }
    }
    red[t] = ss;
    __syncthreads();
    #pragma unroll
    for (int s = 128; s > 0; s >>= 1) {
        if (t < s) red[t] += red[t + s];
        __syncthreads();
    }
    if (t == 0) {
        #pragma unroll
        for (int r = 0; r < NREP; ++r)
            st_f64(&partialsR[(size_t)r * NB + bid], red[0]);   // wave 0
    }

    // ---------------- phase 1: G column (blocks 0..6) ----------------
    if (bid < CD) {
        if (t < SIGLEN) {
            int m = t + 50 - SAMPS * bid;    // conv(delta, h_ps) = shifted h_ps
            cur[t] = (m >= 0 && m < KFILT) ? (double)hA[m] : 0.0;
        }
        __syncthreads();
        for (int f = 0; f < 2; ++f) {
            const float* h = (f == 0) ? hB : hA;   // lowpass, then pulseshape
            if (t < SIGLEN) {
                double acc = 0.0;
                for (int m = 0; m < KFILT; ++m) {
                    int j = t + 50 - m;
                    if (j >= 0 && j < SIGLEN) acc += (double)h[m] * cur[j];
                }
                nxt[t] = acc;
            }
            __syncthreads();
            if (t < SIGLEN) cur[t] = nxt[t];
            __syncthreads();
        }
        if (t < CD) {                         // wave 0: lanes 0..6
            double v = (double)SAMPS * cur[t * SAMPS];
            #pragma unroll
            for (int r = 0; r < NREP; ++r)
                st_f64(&GR[(size_t)r * 64 + t * CD + bid], v);
        }
    }

    // ---------------- pre-barrier hoisted work (norm-independent) ----------
    if (t < 112) sWd1[t] = Wd1[t];
    sWd2[t] = Wd2[t];
    if (t < 16)  { sc1[t] = bd1[t]; sc2[t] = bd2[t]; }
    if (t < MCONST) {
        float ph = (float)(2.0 * 3.14159265358979323846 / (double)MCONST) * (float)t;
        str[t]          = cosf(ph);
        str[MCONST + t] = sinf(ph);
    }
    {   // stage this block's noise rows, coalesced
        size_t base = (size_t)bid * (256 * CD);
        size_t lim  = (size_t)B * CD;
        #pragma unroll
        for (int i = 0; i < CD; ++i) {
            int idx = t + i * 256;
            if (base + idx < lim) snz[idx] = noise[base + idx];
        }
    }
    if (t == 1) {
        int iv = *snr_p;
        float sv = (iv >= -1000 && iv <= 1000) ? (float)iv
                                               : *reinterpret_cast<const float*>(snr_p);
        float snr_lin = powf(10.0f, 0.1f * sv);
        sdenom = sqrtf((float)(8.0 / 7.0) * snr_lin);  // sqrt(2*rate*snr_lin)
    }

    // ---------------- arrival (proven round-5 chain, spread lines) ---------
    // data-store -> vmcnt(0) -> RMW chain -> last arriver sets 8 flags
    __syncthreads();   // all waves finished phase-1 work
    if (t == 0) {
        asm volatile("s_waitcnt vmcnt(0)" ::: "memory");  // wave-0 stores at LLC
        bool last;
        if (NB == 512) {
            unsigned g = (unsigned)bid >> 6;               // 8 groups of 64
            last = false;
            if (add_u32(barBase + (size_t)g * 256) == 63u)
                last = (add_u32(barBase + 2048) == 7u);
        } else {
            last = (add_u32(barBase + 2048) == (unsigned)(NB - 1));
        }
        if (last) {
            #pragma unroll
            for (int r = 0; r < NREP; ++r)
                st_u32(barBase + 2304 + (size_t)r * 256, 1u);
        } else {
            while (ld_u32(barBase + 2304 + (size_t)(bid & (NREP - 1)) * 256) == 0u)
                __builtin_amdgcn_s_sleep(8);
        }
    }
    __syncthreads();

    // ---------------- phase 2: norm reduction (identical in every block) ----
    if (t < 49) sG[t] = ld_f64(&GR[(size_t)rep * 64 + t]);
    {
        double s = 0.0;
        for (int i = t; i < NB; i += 256)
            s += ld_f64(&partialsR[(size_t)rep * NB + i]);
        red[t] = s;
    }
    __syncthreads();
    #pragma unroll
    for (int k = 128; k > 0; k >>= 1) {
        if (t < k) red[t] += red[t + k];
        __syncthreads();
    }
    if (t == 0) snorm = (float)sqrt(red[0]);
    __syncthreads();

    if (row >= B) return;

    float sr[CD], si[CD], sgn[CD];
    #pragma unroll
    for (int o = 0; o < CD; ++o) {
        float es = e[o] / snorm * 70.0f;         // enc / ||enc|| * 70
        float rv = rintf(es);                    // jnp.round = half-to-even
        int xi = (int)rv;
        sgn[o] = (xi < 0) ? -1.0f : 1.0f;
        int idx = (xi < 0 ? -xi : xi) & (MCONST - 1);   // mod(|xi|, 128)
        sr[o] = str[idx];
        si[o] = str[MCONST + idx];
    }

    float res[CD];
    #pragma unroll
    for (int k = 0; k < CD; ++k) {
        double yr = 0.0, yi = 0.0;
        #pragma unroll
        for (int c = 0; c < CD; ++c) {
            double g = sG[k * CD + c];
            yr += g * (double)sr[c];
            yi += g * (double)si[c];
        }
        float ang = atan2f((float)yi, (float)yr);
        float q = ang * (float)(128.0 / (2.0 * 3.14159265358979323846));
        float r = rintf(q);
        float m = fmodf(r, 128.0f);
        if (m < 0.0f) m += 128.0f;               // jnp.mod semantics
        res[k] = m * sgn[k] + snz[t * CD + k] / sdenom;
    }

    float dd[16];
    #pragma unroll
    for (int i = 0; i < 16; ++i) {
        float acc = sc1[i];
        #pragma unroll
        for (int c = 0; c < CD; ++c) acc = fmaf(sWd1[i*CD+c], res[c], acc);
        dd[i] = (acc >= 0.f) ? acc : 0.01f * acc;
    }
    float4* op = reinterpret_cast<float4*>(out + (size_t)row * IN_DIM);
    #pragma unroll
    for (int q4 = 0; q4 < 4; ++q4) {
        float o0[4];
        #pragma unroll
        for (int u = 0; u < 4; ++u) {
            int i = q4 * 4 + u;
            float acc = sc2[i];
            #pragma unroll
            for (int j = 0; j < 16; ++j) acc = fmaf(sWd2[i*16+j], dd[j], acc);
            o0[u] = acc;
        }
        op[q4] = make_float4(o0[0], o0[1], o0[2], o0[3]);
    }
}

// ---------------------------------------------------------------------------
extern "C" void kernel_launch(void* const* d_in, const int* in_sizes, int n_in,
                              void* d_out, int out_size, void* d_ws, size_t ws_size,
                              hipStream_t stream)
{
    const float* x    = (const float*)d_in[0];
    const float* We1  = (const float*)d_in[1];
    const float* be1  = (const float*)d_in[2];
    const float* We2  = (const float*)d_in[3];
    const float* be2  = (const float*)d_in[4];
    const float* Wd1  = (const float*)d_in[5];
    const float* bd1  = (const float*)d_in[6];
    const float* Wd2  = (const float*)d_in[7];
    const float* bd2  = (const float*)d_in[8];
    const float* h_lp = (const float*)d_in[9];
    const float* h_ps = (const float*)d_in[10];
    const float* noise= (const float*)d_in[11];
    const int*   snr  = (const int*)d_in[12];
    float* out = (float*)d_out;

    int B  = in_sizes[0] / IN_DIM;
    int NB = (B + 255) / 256;   // 512 for B=131072 -> exactly 2 blocks/CU

    char* ws = (char*)d_ws;
    double* partialsR = (double*)(ws + 0);       // NREP * NB * 8  (<= 32768)
    double* GR        = (double*)(ws + 32768);   // NREP * 64 * 8 = 4096
    char*   barBase   = ws + 36864;              // counters + flags (4352 B)

    // zero arrival counters + flags (graph-capturable)
    hipMemsetAsync(barBase, 0, 4352, stream);

    k_fused<<<NB, 256, 0, stream>>>(x, We1, be1, We2, be2, Wd1, bd1, Wd2, bd2,
                                    h_lp, h_ps, noise, snr,
                                    partialsR, GR, barBase, out, B, NB);
}

// Round 9
// 33.632 us; speedup vs baseline: 2.4749x; 1.1383x over previous
//
#include <hip/hip_runtime.h>
#include <math.h>

// ---------------------------------------------------------------------------
// Problem constants (from reference)
// ---------------------------------------------------------------------------
#define IN_DIM   16
#define CD       7
#define SAMPS    20
#define KFILT    101
#define SIGLEN   140      // CD * SAMPS
#define MCONST   128      // 2^CD

// ws layout (bytes):
//   [0     .. 4096)   : double partials[512]
//   [4096  .. 4488)   : double G[49]
//   [8192  .. +4.2MB) : float enc[B][8]
// All plain loads/stores — kernel boundary provides release/acquire, so
// k2's plain loads are L2-amortized (the r5/r8 lesson: agent-scope atomic
// loads bypass L2 and serialize at the LLC; don't use them for fan-in).
// ---------------------------------------------------------------------------

__global__ __launch_bounds__(256) void k1_enc(
    const float* __restrict__ x,
    const float* __restrict__ We1, const float* __restrict__ be1,
    const float* __restrict__ We2, const float* __restrict__ be2,
    const float* __restrict__ h_lp, const float* __restrict__ h_ps,
    float* __restrict__ enc, double* __restrict__ partials,
    double* __restrict__ Gd, int B)
{
    int t   = threadIdx.x;
    int bid = blockIdx.x;
    int row = bid * 256 + t;

    __shared__ float  sW1[256], sW2[112], sb1[16], sb2[7];
    __shared__ double red[256];
    __shared__ double cur[SIGLEN], nxt[SIGLEN];
    __shared__ float  hA[KFILT], hB[KFILT];   // h_ps, h_lp

    sW1[t] = We1[t];
    if (t < 112) sW2[t] = We2[t];
    if (t < 16)  sb1[t] = be1[t];
    if (t < 7)   sb2[t] = be2[t];
    if (bid < CD && t < KFILT) { hA[t] = h_ps[t]; hB[t] = h_lp[t]; }
    __syncthreads();

    // encoder
    double ss = 0.0;
    if (row < B) {
        const float4* xp = reinterpret_cast<const float4*>(x + (size_t)row * IN_DIM);
        float4 v0 = xp[0], v1 = xp[1], v2 = xp[2], v3 = xp[3];
        float xr[16] = {v0.x,v0.y,v0.z,v0.w, v1.x,v1.y,v1.z,v1.w,
                        v2.x,v2.y,v2.z,v2.w, v3.x,v3.y,v3.z,v3.w};
        float h[16];
        #pragma unroll
        for (int i = 0; i < 16; ++i) {
            float acc = sb1[i];
            #pragma unroll
            for (int j = 0; j < 16; ++j) acc = fmaf(sW1[i*16+j], xr[j], acc);
            h[i] = (acc >= 0.f) ? acc : 0.01f * acc;
        }
        float e[8];
        #pragma unroll
        for (int o = 0; o < CD; ++o) {
            float acc = sb2[o];
            #pragma unroll
            for (int i = 0; i < 16; ++i) acc = fmaf(sW2[o*16+i], h[i], acc);
            e[o] = acc;
            ss += (double)acc * (double)acc;
        }
        e[7] = 0.f;
        float4* ep = reinterpret_cast<float4*>(enc + (size_t)row * 8);
        ep[0] = make_float4(e[0], e[1], e[2], e[3]);
        ep[1] = make_float4(e[4], e[5], e[6], e[7]);
    }
    red[t] = ss;
    __syncthreads();
    #pragma unroll
    for (int s = 128; s > 0; s >>= 1) {
        if (t < s) red[t] += red[t + s];
        __syncthreads();
    }
    if (t == 0) partials[bid] = red[0];

    // G column (blocks 0..6): delta through truncated 3-conv chain
    if (bid < CD) {
        if (t < SIGLEN) {
            int m = t + 50 - SAMPS * bid;    // conv(delta, h_ps) = shifted h_ps
            cur[t] = (m >= 0 && m < KFILT) ? (double)hA[m] : 0.0;
        }
        __syncthreads();
        for (int f = 0; f < 2; ++f) {
            const float* h = (f == 0) ? hB : hA;   // lowpass, then pulseshape
            if (t < SIGLEN) {
                double acc = 0.0;
                for (int m = 0; m < KFILT; ++m) {
                    int j = t + 50 - m;
                    if (j >= 0 && j < SIGLEN) acc += (double)h[m] * cur[j];
                }
                nxt[t] = acc;
            }
            __syncthreads();
            if (t < SIGLEN) cur[t] = nxt[t];
            __syncthreads();
        }
        if (t < CD) Gd[t * CD + bid] = (double)SAMPS * cur[t * SAMPS];
    }
}

__global__ __launch_bounds__(256) void k2_main(
    const float* __restrict__ enc,
    const float* __restrict__ Wd1, const float* __restrict__ bd1,
    const float* __restrict__ Wd2, const float* __restrict__ bd2,
    const float* __restrict__ noise, const int* __restrict__ snr_p,
    const double* __restrict__ partials, const double* __restrict__ Gd,
    float* __restrict__ out, int B, int NB)
{
    int t   = threadIdx.x;
    int bid = blockIdx.x;
    int row = bid * 256 + t;

    __shared__ float  sV1[112], sc1[16], sV2[256], sc2[16];
    __shared__ float  str[2 * MCONST];
    __shared__ double sG[49];
    __shared__ double red[256];
    __shared__ float  snorm, sdenom;

    sV2[t] = Wd2[t];
    if (t < 112) sV1[t] = Wd1[t];
    if (t < 16)  { sc1[t] = bd1[t]; sc2[t] = bd2[t]; }
    if (t < 49)  sG[t] = Gd[t];
    if (t < MCONST) {
        float ph = (float)(2.0 * 3.14159265358979323846 / (double)MCONST) * (float)t;
        str[t]          = cosf(ph);
        str[MCONST + t] = sinf(ph);
    }
    {   // redundant deterministic norm reduction (plain loads, L2-amortized)
        double s = 0.0;
        for (int i = t; i < NB; i += 256) s += partials[i];
        red[t] = s;
    }
    __syncthreads();
    #pragma unroll
    for (int k = 128; k > 0; k >>= 1) {
        if (t < k) red[t] += red[t + k];
        __syncthreads();
    }
    if (t == 0) snorm = (float)sqrt(red[0]);
    if (t == 1) {
        int iv = *snr_p;
        float sv = (iv >= -1000 && iv <= 1000) ? (float)iv
                                               : *reinterpret_cast<const float*>(snr_p);
        float snr_lin = powf(10.0f, 0.1f * sv);
        sdenom = sqrtf((float)(8.0 / 7.0) * snr_lin);  // sqrt(2*rate*snr_lin)
    }
    __syncthreads();

    if (row >= B) return;

    const float4* ep = reinterpret_cast<const float4*>(enc + (size_t)row * 8);
    float4 e0 = ep[0], e1 = ep[1];
    float ev[7] = {e0.x, e0.y, e0.z, e0.w, e1.x, e1.y, e1.z};

    float sr[CD], si[CD], sgn[CD];
    #pragma unroll
    for (int o = 0; o < CD; ++o) {
        float es = ev[o] / snorm * 70.0f;        // enc / ||enc|| * 70
        float rv = rintf(es);                    // jnp.round = half-to-even
        int xi = (int)rv;
        sgn[o] = (xi < 0) ? -1.0f : 1.0f;
        int idx = (xi < 0 ? -xi : xi) & (MCONST - 1);   // mod(|xi|, 128)
        sr[o] = str[idx];
        si[o] = str[MCONST + idx];
    }

    float res[CD];
    #pragma unroll
    for (int k = 0; k < CD; ++k) {
        double yr = 0.0, yi = 0.0;
        #pragma unroll
        for (int c = 0; c < CD; ++c) {
            double g = sG[k * CD + c];
            yr += g * (double)sr[c];
            yi += g * (double)si[c];
        }
        float ang = atan2f((float)yi, (float)yr);
        float q = ang * (float)(128.0 / (2.0 * 3.14159265358979323846));
        float r = rintf(q);
        float m = fmodf(r, 128.0f);
        if (m < 0.0f) m += 128.0f;               // jnp.mod semantics
        res[k] = m * sgn[k] + noise[(size_t)row * CD + k] / sdenom;
    }

    float dd[16];
    #pragma unroll
    for (int i = 0; i < 16; ++i) {
        float acc = sc1[i];
        #pragma unroll
        for (int c = 0; c < CD; ++c) acc = fmaf(sV1[i*CD+c], res[c], acc);
        dd[i] = (acc >= 0.f) ? acc : 0.01f * acc;
    }
    float4* op = reinterpret_cast<float4*>(out + (size_t)row * IN_DIM);
    #pragma unroll
    for (int q4 = 0; q4 < 4; ++q4) {
        float o0[4];
        #pragma unroll
        for (int u = 0; u < 4; ++u) {
            int i = q4 * 4 + u;
            float acc = sc2[i];
            #pragma unroll
            for (int j = 0; j < 16; ++j) acc = fmaf(sV2[i*16+j], dd[j], acc);
            o0[u] = acc;
        }
        op[q4] = make_float4(o0[0], o0[1], o0[2], o0[3]);
    }
}

// ---------------------------------------------------------------------------
extern "C" void kernel_launch(void* const* d_in, const int* in_sizes, int n_in,
                              void* d_out, int out_size, void* d_ws, size_t ws_size,
                              hipStream_t stream)
{
    const float* x    = (const float*)d_in[0];
    const float* We1  = (const float*)d_in[1];
    const float* be1  = (const float*)d_in[2];
    const float* We2  = (const float*)d_in[3];
    const float* be2  = (const float*)d_in[4];
    const float* Wd1  = (const float*)d_in[5];
    const float* bd1  = (const float*)d_in[6];
    const float* Wd2  = (const float*)d_in[7];
    const float* bd2  = (const float*)d_in[8];
    const float* h_lp = (const float*)d_in[9];
    const float* h_ps = (const float*)d_in[10];
    const float* noise= (const float*)d_in[11];
    const int*   snr  = (const int*)d_in[12];
    float* out = (float*)d_out;

    int B  = in_sizes[0] / IN_DIM;
    int NB = (B + 255) / 256;   // 512 for B=131072

    char* ws = (char*)d_ws;
    double* partials = (double*)(ws + 0);
    double* Gd       = (double*)(ws + 4096);
    float*  enc      = (float*) (ws + 8192);

    k1_enc<<<NB, 256, 0, stream>>>(x, We1, be1, We2, be2, h_lp, h_ps,
                                   enc, partials, Gd, B);
    k2_main<<<NB, 256, 0, stream>>>(enc, Wd1, bd1, Wd2, bd2, noise, snr,
                                    partials, Gd, out, B, NB);
}